// Round 4
// baseline (151.200 us; speedup 1.0000x reference)
//
#include <hip/hip_runtime.h>
#include <hip/hip_cooperative_groups.h>
#include <math.h>

namespace cg = cooperative_groups;

// B=8, N=2048, coords [B,N,3] f32. LDDT loss, upper-triangle formulation:
// both distance matrices are symmetric, so num/den over {j>i} equals the
// full-matrix ratio; j>i also excludes the diagonal (reference's
// true_d > 1e-8 test is vacuous for distinct points).
//
// V5: fuse partial+reduce into ONE cooperative kernel (grid.sync + block-0
// reduce of the L2-warm 9KB of partials). V4 showed the inner loop is NOT
// instruction-bound (-25% LDS instrs, -8% pairs => no delta), so the lever
// is dispatch count, not inner-loop work. Runtime fallback to the proven
// two-kernel path if cooperative launch is rejected.
// Inner loop kept from V4: packed j-tile (3x ds_read_b128 per 2 j-points,
// same-address broadcast, conflict-free), ballot+popcount counting,
// wave-level triangle skip. v_readlane (V3) and uniform-pointer scalar
// loads (V2) both measured SLOWER -- do not revisit.
constexpr int B  = 8;
constexpr int N  = 2048;
constexpr int TI = 256;        // i-points per block (== threads)
constexpr int TJ = 64;         // j-points per block (== one wave)
constexpr int TILES = 144;     // sum_{a=0..7} (32 - 4a): j-tiles with any j>i

template <bool CHECK>
__device__ __forceinline__ void do_pair(
    float jx, float jy, float jz, float ux, float uy, float uz,
    float pix, float piy, float piz, float tix, float tiy, float tiz,
    int jj,
    unsigned& c0, unsigned& c1, unsigned& c2, unsigned& c3, unsigned& cd)
{
    float dx = pix - jx, dy = piy - jy, dz = piz - jz;
    float pd2 = fmaf(dx, dx, fmaf(dy, dy, dz * dz));
    float ex = tix - ux, ey = tiy - uy, ez = tiz - uz;
    float td2 = fmaf(ex, ex, fmaf(ey, ey, ez * ez));

    // local mask (squared domain): true_d < 15
    unsigned long long m = __ballot(td2 < 225.0f);
    // diagonal tile: j>i <=> jj>lane <=> lane in [0,jj) -> constant mask
    if (CHECK) m &= (jj < 64) ? ((1ull << jj) - 1ull) : ~0ull;

    float diff = fabsf(__builtin_amdgcn_sqrtf(pd2) - __builtin_amdgcn_sqrtf(td2));

    // cumulative bins: score = .5*[d<.5] + .25*[d<1] + .125*[d<2] + .125*[d<4]
    c0 += __popcll(m & __ballot(diff < 0.5f));
    c1 += __popcll(m & __ballot(diff < 1.0f));
    c2 += __popcll(m & __ballot(diff < 2.0f));
    c3 += __popcll(m & __ballot(diff < 4.0f));
    cd += __popcll(m);
}

template <bool CHECK>
__device__ __forceinline__ void inner_loop(
    const float4* __restrict__ s4,   // packed j-tile: 3 float4 per 2 j-points
    float pix, float piy, float piz,
    float tix, float tiy, float tiz,
    unsigned& c0, unsigned& c1, unsigned& c2, unsigned& c3, unsigned& cd)
{
    #pragma unroll 4
    for (int q = 0; q < TJ / 2; ++q) {
        // same address across all 64 lanes -> LDS broadcast, conflict-free
        float4 A  = s4[3 * q + 0];  // {p0.x, p0.y, p0.z, t0.x}
        float4 Bq = s4[3 * q + 1];  // {t0.y, t0.z, p1.x, p1.y}
        float4 Cq = s4[3 * q + 2];  // {p1.z, t1.x, t1.y, t1.z}

        do_pair<CHECK>(A.x, A.y, A.z, A.w, Bq.x, Bq.y,
                       pix, piy, piz, tix, tiy, tiz, 2 * q,
                       c0, c1, c2, c3, cd);
        do_pair<CHECK>(Bq.z, Bq.w, Cq.x, Cq.y, Cq.z, Cq.w,
                       pix, piy, piz, tix, tiy, tiz, 2 * q + 1,
                       c0, c1, c2, c3, cd);
    }
}

// shared body: compute this block's (num, den) and store to its private slot
__device__ __forceinline__ void partial_body(
    const float* __restrict__ pred, const float* __restrict__ truec,
    float* __restrict__ part)
{
    const int b = blockIdx.y;
    // decode linear tile index -> (a = i-tile, k = j-subtile rel. index)
    int r = blockIdx.x, a = 0;
    while (r >= 32 - 4 * a) { r -= 32 - 4 * a; ++a; }
    const int k = r;                  // c = 4a + k, k in [0, 32-4a)
    const int i0 = a * TI;
    const int j0 = (4 * a + k) * TJ;
    const int t = threadIdx.x;
    const int w = t >> 6;
    const int lane = t & 63;

    // packed j-tile: sj[6*j .. 6*j+5] = {px,py,pz,tx,ty,tz} of point j0+j
    __shared__ float sj[TJ * 6];
    if (t < TJ) {
        const float* pp = pred  + ((size_t)b * N + j0 + t) * 3;
        const float* tp = truec + ((size_t)b * N + j0 + t) * 3;
        sj[6 * t + 0] = pp[0];
        sj[6 * t + 1] = pp[1];
        sj[6 * t + 2] = pp[2];
        sj[6 * t + 3] = tp[0];
        sj[6 * t + 4] = tp[1];
        sj[6 * t + 5] = tp[2];
    }
    __syncthreads();

    unsigned c0 = 0, c1 = 0, c2 = 0, c3 = 0, cd = 0;

    if (k >= w) {                     // k<w: whole wave is j<i -> zero
        const int i = i0 + t;
        const float* pi = pred  + ((size_t)b * N + i) * 3;
        const float* ti = truec + ((size_t)b * N + i) * 3;
        const float pix = pi[0], piy = pi[1], piz = pi[2];
        const float tix = ti[0], tiy = ti[1], tiz = ti[2];
        const float4* s4 = reinterpret_cast<const float4*>(sj);

        if (k > w) {                  // strictly above diagonal: no check
            inner_loop<false>(s4, pix, piy, piz, tix, tiy, tiz,
                              c0, c1, c2, c3, cd);
        } else {                      // k == w: diagonal 64x64 block
            inner_loop<true>(s4, pix, piy, piz, tix, tiy, tiz,
                             c0, c1, c2, c3, cd);
        }
    }

    // counters are wave-uniform (ballot-derived): lane 0 of each wave has them
    __shared__ float rnum[TI / 64];
    __shared__ float rden[TI / 64];
    if (lane == 0) {
        rnum[w] = 0.125f * (float)(4u * c0 + 2u * c1 + c2 + c3);
        rden[w] = (float)cd;
    }
    __syncthreads();

    if (t == 0) {
        float n = 0.0f, d = 0.0f;
        #pragma unroll
        for (int q = 0; q < TI / 64; ++q) { n += rnum[q]; d += rden[q]; }
        // plain store to this block's private slot -- NO atomics, no memset
        float* slot = part + ((size_t)b * TILES + blockIdx.x) * 2;
        slot[0] = n;
        slot[1] = d;
    }
}

// shared body: reduce part[B][TILES][2] -> out[0]; call with >= 256 threads
// of ONE block (4+ waves; wave w handles batches w, w+4, ...).
__device__ __forceinline__ void reduce_body(
    const float* __restrict__ part, float* __restrict__ out,
    int t, int nwaves)
{
    const int w = t >> 6;
    const int l = t & 63;

    __shared__ float acc[B];
    for (int bb = w; bb < B; bb += nwaves) {
        float n = 0.0f, d = 0.0f;
        for (int s = l; s < TILES; s += 64) {
            const float* slot = part + ((size_t)bb * TILES + s) * 2;
            n += slot[0];
            d += slot[1];
        }
        #pragma unroll
        for (int off = 32; off > 0; off >>= 1) {
            n += __shfl_down(n, off, 64);
            d += __shfl_down(d, off, 64);
        }
        if (l == 0) acc[bb] = 1.0f - n / fmaxf(d, 1e-8f);
    }
    __syncthreads();

    if (t == 0) {
        float s = 0.0f;
        #pragma unroll
        for (int b = 0; b < B; ++b) s += acc[b];
        out[0] = s / (float)B;
    }
}

// ---- fused cooperative kernel: partial + grid.sync + block-0 reduce ----
__global__ __launch_bounds__(TI) void lddt_fused(
    const float* __restrict__ pred, const float* __restrict__ truec,
    float* __restrict__ part, float* __restrict__ out)
{
    partial_body(pred, truec, part);
    cg::this_grid().sync();
    if (blockIdx.x == 0 && blockIdx.y == 0) {
        reduce_body(part, out, threadIdx.x, TI / 64);
    }
}

// ---- fallback two-kernel path (proven, V1/V4) ----
__global__ __launch_bounds__(TI) void lddt_partial(
    const float* __restrict__ pred, const float* __restrict__ truec,
    float* __restrict__ part)
{
    partial_body(pred, truec, part);
}

__global__ __launch_bounds__(512) void lddt_reduce(
    const float* __restrict__ part, float* __restrict__ out)
{
    // 8 waves: wave w reduces batch w
    reduce_body(part, out, threadIdx.x, 512 / 64);
}

extern "C" void kernel_launch(void* const* d_in, const int* in_sizes, int n_in,
                              void* d_out, int out_size, void* d_ws, size_t ws_size,
                              hipStream_t stream)
{
    const float* pred  = (const float*)d_in[0];
    const float* truec = (const float*)d_in[1];
    float* out  = (float*)d_out;
    float* part = (float*)d_ws;   // B*TILES*2 floats = 9216 B

    dim3 grid(TILES, B);
    void* args[4] = { (void*)&pred, (void*)&truec, (void*)&part, (void*)&out };
    hipError_t err = hipLaunchCooperativeKernel(
        reinterpret_cast<void*>(lddt_fused), grid, dim3(TI), args, 0, stream);
    if (err != hipSuccess) {
        // capture-safe fallback: the proven two-kernel path
        lddt_partial<<<grid, TI, 0, stream>>>(pred, truec, part);
        lddt_reduce<<<1, 512, 0, stream>>>(part, out);
    }
}